// Round 1
// baseline (2699.862 us; speedup 1.0000x reference)
//
#include <hip/hip_runtime.h>
#include <math.h>

// ---------------------------------------------------------------------------
// DsDTW pipeline, fp32 reference-faithful implementation (round 0).
// B=32, C_IN=12, T=4095, D=128, L=1024, GAMMA=5.0
//
// ws layout (floats):
//   h      @ 0          4,194,304   [32,1024,128] conv+pool+relu+mask
//   qkv    @ 4194304   12,582,912   [32,1024,384]
//   t0     @ 16777216   4,194,304   scratch (attn out, then ff2 out / h2)
//   t1     @ 20971520   4,194,304   scratch (h+sa, then LN1 -> h1)
//   t2     @ 25165824   4,194,304   scratch (ff hidden)
//   norms  @ 29360128      32,768   |h[b,l]|^2
//   rmax   @ 29392896      32,768   softmax row max
//   rsum   @ 29425664      32,768   softmax 1/rowsum
//   mnmx   @ 29458432          64   per-sample R min/max
//   Mb     @ 29458496  33,554,432   [32,1024,1024] D -> R -> scores (in place)
// total ~252 MB
// ---------------------------------------------------------------------------

#define L_SEQ 1024
#define DM 128

// ------------------------- conv + pool + relu + mask -----------------------
__global__ __launch_bounds__(128) void conv_k(
    const float* __restrict__ x, const float* __restrict__ w,
    const float* __restrict__ cb, const float* __restrict__ mask,
    float* __restrict__ h)
{
    int b = blockIdx.x;
    int l0 = blockIdx.y * 8;
    int d = threadIdx.x;
    __shared__ float xs[12][36];  // x indices 4*l0-2 .. 4*l0+32 (35 values)
    for (int v = d; v < 12 * 35; v += 128) {
        int c = v / 35, off = v % 35;
        int gi = 4 * l0 - 2 + off;
        xs[c][off] = (gi >= 0 && gi < 4095) ? x[((long)b * 12 + c) * 4095 + gi] : 0.f;
    }
    __syncthreads();
    float s[8];
#pragma unroll
    for (int l = 0; l < 8; ++l) s[l] = 0.f;
    for (int c = 0; c < 12; ++c) {
        const float* wp = w + (d * 12 + c) * 4;
        float w0 = wp[0], w1 = wp[1], w2 = wp[2], w3 = wp[3];
        // effective pooled filter over u = p+k (p,k in [0,4)), scale 1/4 at end
        float e0 = w0, e1 = w0 + w1, e2 = w0 + w1 + w2, e3 = w0 + w1 + w2 + w3;
        float e4 = w1 + w2 + w3, e5 = w2 + w3, e6 = w3;
#pragma unroll
        for (int l = 0; l < 8; ++l) {
            int ba = 4 * l;
            s[l] += xs[c][ba] * e0 + xs[c][ba + 1] * e1 + xs[c][ba + 2] * e2 +
                    xs[c][ba + 3] * e3 + xs[c][ba + 4] * e4 + xs[c][ba + 5] * e5 +
                    xs[c][ba + 6] * e6;
        }
    }
    float cbd = cb[d];
#pragma unroll
    for (int l = 0; l < 8; ++l) {
        int gl = l0 + l;
        float val = fmaxf(cbd + 0.25f * s[l], 0.f) * mask[b * L_SEQ + gl];
        h[((long)(b * L_SEQ + gl)) * DM + d] = val;
    }
}

// ------------------------------- row norms ---------------------------------
__global__ __launch_bounds__(128) void norm_k(const float* __restrict__ h,
                                              float* __restrict__ norms)
{
    long row = blockIdx.x;
    int d = threadIdx.x;
    float v = h[row * DM + d];
    __shared__ float red[128];
    red[d] = v * v;
    __syncthreads();
    for (int s = 64; s > 0; s >>= 1) {
        if (d < s) red[d] += red[d + s];
        __syncthreads();
    }
    if (d == 0) norms[row] = red[0];
}

// ------------------------------ tiled GEMM ---------------------------------
enum GMode { M_D2, M_QKV, M_SCORES, M_ATTNV, M_WOUT, M_FF1, M_FF2, M_LIN };

template <int MODE, bool BT>
__global__ __launch_bounds__(256) void gemm_k(
    const float* __restrict__ A, const float* __restrict__ B, float* __restrict__ C,
    int M, int N, int K, int lda, int ldb, int ldc,
    long sA, long sB, long sC,
    const float* __restrict__ e0, const float* __restrict__ e1)
{
    int z = blockIdx.z;
    A += (long)z * sA;
    B += (long)z * sB;
    C += (long)z * sC;
    __shared__ float As[16][65];
    __shared__ float Bs[16][65];
    int tid = threadIdx.x;
    int tx = tid & 15, ty = tid >> 4;
    int m0 = blockIdx.x * 64, n0 = blockIdx.y * 64;
    float acc[4][4] = {};
    int am = tid >> 2;          // 0..63 (row within A tile)
    int ak = (tid & 3) << 2;    // 0,4,8,12 (k within chunk)
    float rmaxv = 0.f;
    if (MODE == M_ATTNV) rmaxv = e0[(long)z * L_SEQ + m0 + am];

    for (int kk = 0; kk < K; kk += 16) {
        {   // A tile: rows m0+am (M is multiple of 64 in all uses)
            const float4 av =
                *reinterpret_cast<const float4*>(A + (long)(m0 + am) * lda + kk + ak);
            float4 t = av;
            if (MODE == M_ATTNV) {
                t.x = __expf(t.x - rmaxv);
                t.y = __expf(t.y - rmaxv);
                t.z = __expf(t.z - rmaxv);
                t.w = __expf(t.w - rmaxv);
            }
            As[ak + 0][am] = t.x;
            As[ak + 1][am] = t.y;
            As[ak + 2][am] = t.z;
            As[ak + 3][am] = t.w;
        }
        if (BT) {   // B is [N,K] row-major
            int n = n0 + am;
            float4 bv = {0.f, 0.f, 0.f, 0.f};
            if (n < N)
                bv = *reinterpret_cast<const float4*>(B + (long)n * ldb + kk + ak);
            Bs[ak + 0][am] = bv.x;
            Bs[ak + 1][am] = bv.y;
            Bs[ak + 2][am] = bv.z;
            Bs[ak + 3][am] = bv.w;
        } else {    // B is [K,N] row-major
            int bk = tid >> 4;           // 0..15
            int bn = (tid & 15) << 2;    // 0..60
            float4 bv =
                *reinterpret_cast<const float4*>(B + (long)(kk + bk) * ldb + n0 + bn);
            Bs[bk][bn + 0] = bv.x;
            Bs[bk][bn + 1] = bv.y;
            Bs[bk][bn + 2] = bv.z;
            Bs[bk][bn + 3] = bv.w;
        }
        __syncthreads();
#pragma unroll
        for (int kc = 0; kc < 16; ++kc) {
            float a0 = As[kc][ty * 4 + 0], a1 = As[kc][ty * 4 + 1];
            float a2 = As[kc][ty * 4 + 2], a3 = As[kc][ty * 4 + 3];
            float b0 = Bs[kc][tx * 4 + 0], b1 = Bs[kc][tx * 4 + 1];
            float b2 = Bs[kc][tx * 4 + 2], b3 = Bs[kc][tx * 4 + 3];
            acc[0][0] += a0 * b0; acc[0][1] += a0 * b1; acc[0][2] += a0 * b2; acc[0][3] += a0 * b3;
            acc[1][0] += a1 * b0; acc[1][1] += a1 * b1; acc[1][2] += a1 * b2; acc[1][3] += a1 * b3;
            acc[2][0] += a2 * b0; acc[2][1] += a2 * b1; acc[2][2] += a2 * b2; acc[2][3] += a2 * b3;
            acc[3][0] += a3 * b0; acc[3][1] += a3 * b1; acc[3][2] += a3 * b2; acc[3][3] += a3 * b3;
        }
        __syncthreads();
    }

#pragma unroll
    for (int i = 0; i < 4; ++i) {
        int gi = m0 + ty * 4 + i;
#pragma unroll
        for (int j = 0; j < 4; ++j) {
            int gj = n0 + tx * 4 + j;
            float v = acc[i][j];
            long idx = (long)gi * ldc + gj;
            if (MODE == M_D2) {
                C[idx] = e0[gi] + e0[(long)z * L_SEQ + gj] - 2.f * v;
            } else if (MODE == M_QKV) {
                C[idx] = v + e0[gj];
            } else if (MODE == M_SCORES) {
                float mn = e0[2 * z], mx = e0[2 * z + 1];
                float rn = (C[idx] - mn) / (mx - mn) + 1.f;
                float kp = (e1[(long)z * L_SEQ + gj] > 0.f) ? 0.f : -INFINITY;
                C[idx] = v * 0.08838834764831845f + rn + kp;
            } else if (MODE == M_ATTNV) {
                C[idx] = v * e1[(long)z * L_SEQ + gi];
            } else if (MODE == M_WOUT) {
                C[idx] = v + e0[gj] + e1[idx];
            } else if (MODE == M_FF1) {
                C[idx] = fmaxf(v + e0[gj], 0.f);
            } else if (MODE == M_FF2) {
                C[idx] = v + e0[gj] + e1[idx];
            } else if (MODE == M_LIN) {
                if (gj < N) C[idx] = v * e0[gi];
            }
        }
    }
}

// ------------------------------- soft-DTW ----------------------------------
__global__ __launch_bounds__(1024) void dtw_k(float* __restrict__ Mb,
                                              float* __restrict__ minmax)
{
    int b = blockIdx.x;
    float* R = Mb + (long)b * L_SEQ * L_SEQ;
    int i = threadIdx.x;
    __shared__ float buf[3][L_SEQ];
    const float INF = INFINITY;
    buf[1][i] = INF;
    buf[2][i] = INF;
    __syncthreads();
    float vmin = INF, vmax = -INF;
    int cur = 0, p1 = 2, p2 = 1;
    for (int k = 0; k < 2 * L_SEQ - 1; ++k) {
        int j = k - i;
        float r = INF;
        if (j >= 0 && j < L_SEQ) {
            float r_l = buf[p1][i];
            float r_u = (i == 0) ? INF : buf[p1][i - 1];
            float r_ul = (i == 0) ? ((k == 0) ? 0.f : INF) : buf[p2][i - 1];
            float m = fminf(r_ul, fminf(r_u, r_l));
            // m is finite for every valid cell; INF neighbors contribute exp(-inf)=0
            float s = __expf((m - r_ul) * 0.2f) + __expf((m - r_u) * 0.2f) +
                      __expf((m - r_l) * 0.2f);
            float smin = m - 5.0f * __logf(s);
            long idx = (long)i * L_SEQ + j;
            r = R[idx] + smin;   // in-place: D -> R
            R[idx] = r;
            vmin = fminf(vmin, r);
            vmax = fmaxf(vmax, r);
        }
        buf[cur][i] = r;
        __syncthreads();
        int t = cur; cur = p2; p2 = p1; p1 = t;
    }
    // block min/max reduce
    buf[0][i] = vmin;
    buf[1][i] = vmax;
    __syncthreads();
    for (int s = 512; s > 0; s >>= 1) {
        if (i < s) {
            buf[0][i] = fminf(buf[0][i], buf[0][i + s]);
            buf[1][i] = fmaxf(buf[1][i], buf[1][i + s]);
        }
        __syncthreads();
    }
    if (i == 0) {
        minmax[2 * b] = buf[0][0];
        minmax[2 * b + 1] = buf[1][0];
    }
}

// --------------------------- softmax row stats -----------------------------
__global__ __launch_bounds__(256) void smax_k(const float* __restrict__ S,
                                              float* __restrict__ rmax,
                                              float* __restrict__ rsuminv)
{
    long row = blockIdx.x;
    const float4 v = reinterpret_cast<const float4*>(S + row * L_SEQ)[threadIdx.x];
    int t = threadIdx.x;
    __shared__ float red[256];
    red[t] = fmaxf(fmaxf(v.x, v.y), fmaxf(v.z, v.w));
    __syncthreads();
    for (int s = 128; s > 0; s >>= 1) {
        if (t < s) red[t] = fmaxf(red[t], red[t + s]);
        __syncthreads();
    }
    float mx = red[0];
    __syncthreads();
    red[t] = __expf(v.x - mx) + __expf(v.y - mx) + __expf(v.z - mx) + __expf(v.w - mx);
    __syncthreads();
    for (int s = 128; s > 0; s >>= 1) {
        if (t < s) red[t] += red[t + s];
        __syncthreads();
    }
    if (t == 0) {
        rmax[row] = mx;
        rsuminv[row] = 1.f / red[0];
    }
}

// ------------------------------- layernorm ---------------------------------
__global__ __launch_bounds__(128) void ln_k(float* __restrict__ X,
                                            const float* __restrict__ g,
                                            const float* __restrict__ b)
{
    long row = blockIdx.x;
    int d = threadIdx.x;
    float x = X[row * DM + d];
    __shared__ float s1[128];
    __shared__ float s2[128];
    s1[d] = x;
    s2[d] = x * x;
    __syncthreads();
    for (int s = 64; s > 0; s >>= 1) {
        if (d < s) { s1[d] += s1[d + s]; s2[d] += s2[d + s]; }
        __syncthreads();
    }
    float mean = s1[0] * (1.f / 128.f);
    float var = s2[0] * (1.f / 128.f) - mean * mean;
    X[row * DM + d] = (x - mean) * rsqrtf(var + 1e-5f) * g[d] + b[d];
}

// -------------------------------- lengths ----------------------------------
__global__ __launch_bounds__(256) void len_k(const float* __restrict__ mask,
                                             float* __restrict__ out)
{
    int b = blockIdx.x;
    int t = threadIdx.x;
    const float4 v = reinterpret_cast<const float4*>(mask + b * L_SEQ)[t];
    __shared__ float red[256];
    red[t] = v.x + v.y + v.z + v.w;
    __syncthreads();
    for (int s = 128; s > 0; s >>= 1) {
        if (t < s) red[t] += red[t + s];
        __syncthreads();
    }
    if (t == 0) out[b] = red[0];
}

// ------------------------------- launcher ----------------------------------
extern "C" void kernel_launch(void* const* d_in, const int* in_sizes, int n_in,
                              void* d_out, int out_size, void* d_ws, size_t ws_size,
                              hipStream_t stream)
{
    const float* x      = (const float*)d_in[0];
    const float* mask   = (const float*)d_in[1];
    const float* conv_w = (const float*)d_in[2];
    const float* conv_b = (const float*)d_in[3];
    const float* w_in   = (const float*)d_in[4];
    const float* b_in   = (const float*)d_in[5];
    const float* w_out  = (const float*)d_in[6];
    const float* b_out  = (const float*)d_in[7];
    const float* w_ff1  = (const float*)d_in[8];
    const float* b_ff1  = (const float*)d_in[9];
    const float* w_ff2  = (const float*)d_in[10];
    const float* b_ff2  = (const float*)d_in[11];
    const float* ln1_g  = (const float*)d_in[12];
    const float* ln1_b  = (const float*)d_in[13];
    const float* ln2_g  = (const float*)d_in[14];
    const float* ln2_b  = (const float*)d_in[15];
    const float* w_lin  = (const float*)d_in[16];
    float* out = (float*)d_out;

    float* ws    = (float*)d_ws;
    float* h     = ws;
    float* qkv   = ws + 4194304L;
    float* t0    = ws + 16777216L;
    float* t1    = ws + 20971520L;
    float* t2    = ws + 25165824L;
    float* norms = ws + 29360128L;
    float* rmax  = ws + 29392896L;
    float* rsum  = ws + 29425664L;
    float* mnmx  = ws + 29458432L;
    float* Mb    = ws + 29458496L;

    // 1) conv + pool + relu + mask -> h
    conv_k<<<dim3(32, 128), 128, 0, stream>>>(x, conv_w, conv_b, mask, h);
    // 2) per-row squared norms
    norm_k<<<32768, 128, 0, stream>>>(h, norms);
    // 3) pairwise distance D[b,i,j] = |h0_i|^2 + |hb_j|^2 - 2 h0_i . hb_j
    gemm_k<M_D2, true><<<dim3(16, 16, 32), 256, 0, stream>>>(
        h, h, Mb, 1024, 1024, 128, 128, 128, 1024,
        0L, 131072L, 1048576L, norms, nullptr);
    // 4) soft-DTW in place (D -> R) + per-sample min/max
    dtw_k<<<32, 1024, 0, stream>>>(Mb, mnmx);
    // 5) qkv projection
    gemm_k<M_QKV, true><<<dim3(512, 6, 1), 256, 0, stream>>>(
        h, w_in, qkv, 32768, 384, 128, 128, 128, 384,
        0L, 0L, 0L, b_in, nullptr);
    // 6) scores = q k^T/sqrt(128) + norm(R) + keypad  (in place over R)
    gemm_k<M_SCORES, true><<<dim3(16, 16, 32), 256, 0, stream>>>(
        qkv, qkv + 128, Mb, 1024, 1024, 128, 384, 384, 1024,
        393216L, 393216L, 1048576L, mnmx, mask);
    // 7) softmax row stats
    smax_k<<<32768, 256, 0, stream>>>(Mb, rmax, rsum);
    // 8) attn @ v (softmax applied on the fly)
    gemm_k<M_ATTNV, false><<<dim3(16, 2, 32), 256, 0, stream>>>(
        Mb, qkv + 256, t0, 1024, 128, 1024, 1024, 384, 128,
        1048576L, 393216L, 131072L, rmax, rsum);
    // 9) sa @ w_out^T + b_out + h -> t1
    gemm_k<M_WOUT, true><<<dim3(512, 2, 1), 256, 0, stream>>>(
        t0, w_out, t1, 32768, 128, 128, 128, 128, 128,
        0L, 0L, 0L, b_out, h);
    // 10) LN1 in place -> h1
    ln_k<<<32768, 128, 0, stream>>>(t1, ln1_g, ln1_b);
    // 11) ff hidden = relu(h1 @ w_ff1^T + b_ff1)
    gemm_k<M_FF1, true><<<dim3(512, 2, 1), 256, 0, stream>>>(
        t1, w_ff1, t2, 32768, 128, 128, 128, 128, 128,
        0L, 0L, 0L, b_ff1, nullptr);
    // 12) ff out + residual -> t0
    gemm_k<M_FF2, true><<<dim3(512, 2, 1), 256, 0, stream>>>(
        t2, w_ff2, t0, 32768, 128, 128, 128, 128, 128,
        0L, 0L, 0L, b_ff2, t1);
    // 13) LN2 in place -> h2
    ln_k<<<32768, 128, 0, stream>>>(t0, ln2_g, ln2_b);
    // 14) final linear (N=16) * mask -> out
    gemm_k<M_LIN, true><<<dim3(512, 1, 1), 256, 0, stream>>>(
        t0, w_lin, out, 32768, 16, 128, 128, 128, 16,
        0L, 0L, 0L, mask, nullptr);
    // 15) lengths
    len_k<<<32, 256, 0, stream>>>(mask, out + 32768L * 16);
}